// Round 1
// 104.270 us; speedup vs baseline: 1.0031x; 1.0031x over previous
//
#include <hip/hip_runtime.h>
#include <math.h>

// Problem constants
#define PB 8
#define PT 12
#define PN 307
#define NP 320                      // padded N for MFMA tiling
#define SCALE 0.35355339059327373f  // 1/sqrt(8)

typedef short bf16x8 __attribute__((ext_vector_type(8)));
typedef float f32x4  __attribute__((ext_vector_type(4)));
// 4-byte-aligned vectors for rows whose base is only 4B-aligned (307-stride)
typedef int   i32x4u __attribute__((ext_vector_type(4), aligned(4)));
typedef float f32x4u __attribute__((ext_vector_type(4), aligned(4)));

__device__ __forceinline__ unsigned short f32_to_bf16(float v) {
    unsigned u = __float_as_uint(v);
    u += 0x7FFFu + ((u >> 16) & 1u);   // RNE
    return (unsigned short)(u >> 16);
}

__device__ __forceinline__ bf16x8 pack8(float4 lo, float4 hi) {
    bf16x8 r;
    r[0] = (short)f32_to_bf16(lo.x); r[1] = (short)f32_to_bf16(lo.y);
    r[2] = (short)f32_to_bf16(lo.z); r[3] = (short)f32_to_bf16(lo.w);
    r[4] = (short)f32_to_bf16(hi.x); r[5] = (short)f32_to_bf16(hi.y);
    r[6] = (short)f32_to_bf16(hi.z); r[7] = (short)f32_to_bf16(hi.w);
    return r;
}

// ---------------------------------------------------------------------------
// Kernel A — EXACT R6/R9 version (measured-good; do not touch).
// ---------------------------------------------------------------------------
__global__ __launch_bounds__(256) void qk_proj_kernel(
    const float* __restrict__ x,
    const float* __restrict__ Wq, const float* __restrict__ bq,
    const float* __restrict__ Wk, const float* __restrict__ bk,
    unsigned short* __restrict__ qws, unsigned short* __restrict__ kws)
{
    const int tid  = threadIdx.x;
    const int lane = tid & 63;
    const int wv   = tid >> 6;
    const int wn   = wv & 1;
    const int we   = wv >> 1;
    const int chunk = blockIdx.x % 10;
    const int bt    = blockIdx.x / 10;
    const int b = bt / PT, t = bt % PT;
    const int rlo = lane & 15;
    const int kq  = lane >> 4;
    const int n0  = chunk * 32 + wn * 16;        // wave's n-tile base

    const int nn = min(n0 + rlo, PN - 1);
    const float* xrow = x + ((size_t)b * 64 * PT + t) * PN + nn;  // + c*PT*PN
    bf16x8 a[2];
    #pragma unroll
    for (int ks = 0; ks < 2; ++ks) {
        #pragma unroll
        for (int j = 0; j < 8; ++j) {
            const int c = ks * 32 + kq * 8 + j;
            a[ks][j] = (short)f32_to_bf16(xrow[(size_t)c * PT * PN]);
        }
    }

    f32x4 accq[2] = {}, acck[2] = {};
    #pragma unroll
    for (int eti = 0; eti < 2; ++eti) {
        const int e_row = we * 32 + eti * 16 + rlo;
        const float* wq_r = Wq + (size_t)e_row * 64 + kq * 8;
        const float* wk_r = Wk + (size_t)e_row * 64 + kq * 8;
        #pragma unroll
        for (int ks = 0; ks < 2; ++ks) {
            const bf16x8 bqf = pack8(*(const float4*)(wq_r + ks * 32),
                                     *(const float4*)(wq_r + ks * 32 + 4));
            const bf16x8 bkf = pack8(*(const float4*)(wk_r + ks * 32),
                                     *(const float4*)(wk_r + ks * 32 + 4));
            accq[eti] = __builtin_amdgcn_mfma_f32_16x16x32_bf16(a[ks], bqf, accq[eti], 0, 0, 0);
            acck[eti] = __builtin_amdgcn_mfma_f32_16x16x32_bf16(a[ks], bkf, acck[eti], 0, 0, 0);
        }
    }

    #pragma unroll
    for (int eti = 0; eti < 2; ++eti) {
        const int e = we * 32 + eti * 16 + rlo;
        const float bqv = bq[e], bkv = bk[e];
        #pragma unroll
        for (int r = 0; r < 4; ++r) {
            const int n = n0 + kq * 4 + r;
            if (n < PN) {
                qws[((size_t)bt * NP + n) * 64 + e] = f32_to_bf16(accq[eti][r] + bqv);
                kws[((size_t)bt * NP + n) * 64 + e] = f32_to_bf16(acck[eti][r] + bkv);
            }
        }
    }
}

// ---------------------------------------------------------------------------
// Kernel B v8 — v7's proven math, but TLP instead of ILP.
// v7 ran 480 blocks x 4 waves = 1.9 waves/SIMD with a serial tt=0..3 chain
// gated on ~17 scattered 16B fragment loads per iter: latency-bound.
// v8 gives each (b,t,ntile) its own block: grid 1920 -> ~7.5 blocks/CU,
// ~7.5 waves/SIMD. Mask (3 MB) and kws (3.9 MB) are L2-resident, so the
// lost per-block t-reuse costs L2 BW, not HBM. Softmax combine (one
// barrier, wave publishes (mx, sum); gsum = sum_w * exp(mx_w - gmx)) is
// bit-identical to v7 -> absmax unchanged.
// ---------------------------------------------------------------------------
__global__ __launch_bounds__(256) void attn_kernel(
    const unsigned short* __restrict__ qws,
    const unsigned short* __restrict__ kws,
    const int* __restrict__ mask,
    float* __restrict__ out)
{
    __shared__ float2 red[4][16];            // (mx, sum) per wave per n-col

    const int tid  = threadIdx.x;
    const int lane = tid & 63;
    const int wm   = tid >> 6;               // m-quarter (4 waves/block)
    const int bid   = blockIdx.x;
    const int ntile = bid % 20;
    const int bt    = bid / 20;              // b*PT + t
    const int b     = bt / PT;
    const int ng  = ntile * 16;
    const int nl  = lane & 15;
    const int kq  = lane >> 4;
    const int n   = ng + nl;
    const int nn  = (n < PN) ? n : (PN - 1); // clamp for mask row reads

    // ---- mask fragments for this block's 16 n-rows
    const int* mrow = mask + ((size_t)b * PN + nn) * PN;
    i32x4u mv[5];
    #pragma unroll
    for (int i = 0; i < 5; ++i)
        mv[i] = *(const i32x4u*)(mrow + (wm * 5 + i) * 16 + kq * 4);

    // ---- Q/K fragments (qws/kws padded to NP=320, so n up to 319 is safe;
    //      garbage pad columns stay confined to their own nl lane group)
    const unsigned short* qb = qws + ((size_t)bt * NP + n) * 64 + kq * 8;
    const unsigned short* kb = kws + ((size_t)bt * NP + nl) * 64 + kq * 8;

    const bf16x8 bq0 = *(const bf16x8*)(qb);
    const bf16x8 bq1 = *(const bf16x8*)(qb + 32);

    f32x4 acc[5] = {};
    #pragma unroll
    for (int i = 0; i < 5; ++i) {
        const unsigned short* kp = kb + (size_t)(wm * 5 + i) * 16 * 64;
        const bf16x8 ka = *(const bf16x8*)(kp);
        const bf16x8 kc = *(const bf16x8*)(kp + 32);
        acc[i] = __builtin_amdgcn_mfma_f32_16x16x32_bf16(ka, bq0, acc[i], 0, 0, 0);
        acc[i] = __builtin_amdgcn_mfma_f32_16x16x32_bf16(kc, bq1, acc[i], 0, 0, 0);
    }

    // ---- mask + scale, wave-local max over 20 m-values
    float mx = -INFINITY;
    #pragma unroll
    for (int i = 0; i < 5; ++i) {
        const int ct = wm * 5 + i;
        const int m0 = ct * 16 + kq * 4;
        float sv[4];
        sv[0] = mv[i][0] ? acc[i][0] * SCALE : -1e9f;
        sv[1] = mv[i][1] ? acc[i][1] * SCALE : -1e9f;
        sv[2] = mv[i][2] ? acc[i][2] * SCALE : -1e9f;
        sv[3] = mv[i][3] ? acc[i][3] * SCALE : -1e9f;
        if (ct == 19) {                  // pad columns m >= 307 (wave-uniform)
            #pragma unroll
            for (int r = 0; r < 4; ++r)
                if (m0 + r >= PN) sv[r] = -INFINITY;
        }
        #pragma unroll
        for (int r = 0; r < 4; ++r) { acc[i][r] = sv[r]; mx = fmaxf(mx, sv[r]); }
    }
    mx = fmaxf(mx, __shfl_xor(mx, 16));
    mx = fmaxf(mx, __shfl_xor(mx, 32));   // mx >= -1e9 always (307 valid m)

    // ---- wave-local sum of exp(s - mx)
    float sum = 0.f;
    #pragma unroll
    for (int i = 0; i < 5; ++i) {
        #pragma unroll
        for (int r = 0; r < 4; ++r) {
            const float pw = __expf(acc[i][r] - mx);
            acc[i][r] = pw;
            sum += pw;
        }
    }
    sum += __shfl_xor(sum, 16);
    sum += __shfl_xor(sum, 32);

    if (lane < 16) red[wm][lane] = make_float2(mx, sum);
    __syncthreads();                      // the ONLY barrier

    const float2 r0 = red[0][nl], r1 = red[1][nl];
    const float2 r2v = red[2][nl], r3 = red[3][nl];
    const float gmx = fmaxf(fmaxf(r0.x, r1.x), fmaxf(r2v.x, r3.x));
    const float gsum = r0.y * __expf(r0.x - gmx) + r1.y * __expf(r1.x - gmx)
                     + r2v.y * __expf(r2v.x - gmx) + r3.y * __expf(r3.x - gmx);
    const float factor = __expf(mx - gmx) / gsum;

    if (n < PN) {
        float* orow = out + ((size_t)bt * PN + n) * PN;
        #pragma unroll
        for (int i = 0; i < 5; ++i) {
            const int ct = wm * 5 + i;
            const int m0 = ct * 16 + kq * 4;
            if (ct < 19) {
                f32x4u o;
                o[0] = acc[i][0] * factor; o[1] = acc[i][1] * factor;
                o[2] = acc[i][2] * factor; o[3] = acc[i][3] * factor;
                *(f32x4u*)(orow + m0) = o;
            } else {
                #pragma unroll
                for (int r = 0; r < 4; ++r)
                    if (m0 + r < PN) orow[m0 + r] = acc[i][r] * factor;
            }
        }
    }
}

extern "C" void kernel_launch(void* const* d_in, const int* in_sizes, int n_in,
                              void* d_out, int out_size, void* d_ws, size_t ws_size,
                              hipStream_t stream) {
    const float* x  = (const float*)d_in[0];
    const int* mask = (const int*)d_in[1];
    const float* Wq = (const float*)d_in[2];
    const float* bq = (const float*)d_in[3];
    const float* Wk = (const float*)d_in[4];
    const float* bk = (const float*)d_in[5];
    float* out = (float*)d_out;

    // workspace: qws bf16 [96][320][64], kws bf16 [96][320][64]  (7.86 MB)
    unsigned short* qws = (unsigned short*)d_ws;
    unsigned short* kws = qws + (size_t)96 * NP * 64;

    qk_proj_kernel<<<dim3(96 * 10), dim3(256), 0, stream>>>(x, Wq, bq, Wk, bk, qws, kws);
    attn_kernel<<<dim3(96 * 20), dim3(256), 0, stream>>>(qws, kws, mask, out);
}